// Round 2
// baseline (110.162 us; speedup 1.0000x reference)
//
#include <hip/hip_runtime.h>

// out[i] = sum_k targets[i,k] * temporal_bases[batch_indices[1],k] * scaling[k]
// B=8192, K=1024, T=16384. Matvec; memory-bound on the 33.6 MB `targets` read.
//
// Design: one wave per 2 rows. Each lane caches its 16 weight values
// w[k] = wrow[k]*scaling[k] in registers (loaded once), so the inner loop
// issues ONLY the HBM-bound targets loads (4 float4 per row, 8 in flight).

#define KDIM 1024

__global__ __launch_bounds__(256) void recompose_col1_kernel(
    const float* __restrict__ targets,        // (B, K)
    const float* __restrict__ temporal_bases, // (T, K)
    const float* __restrict__ scaling,        // (K,)
    const int*   __restrict__ batch_indices,  // (B,)
    float*       __restrict__ out)            // (B,)
{
    const int wave = threadIdx.x >> 6;   // 0..3
    const int lane = threadIdx.x & 63;
    const int row0 = (blockIdx.x << 2) + wave;   // rows [0, 4096)
    const int row1 = row0 + 4096;                // rows [4096, 8192)

    const long long sel = (long long)batch_indices[1];
    const float* __restrict__ wrow = temporal_bases + sel * (long long)KDIM;

    // Load per-lane weights once: k = j*256 + lane*4, j in [0,4)
    float4 w[4];
    #pragma unroll
    for (int j = 0; j < 4; ++j) {
        const int k = (j << 8) + (lane << 2);
        const float4 b = *(const float4*)(wrow + k);
        const float4 s = *(const float4*)(scaling + k);
        w[j].x = b.x * s.x;
        w[j].y = b.y * s.y;
        w[j].z = b.z * s.z;
        w[j].w = b.w * s.w;
    }

    const float* __restrict__ t0 = targets + (long long)row0 * (long long)KDIM;
    const float* __restrict__ t1 = targets + (long long)row1 * (long long)KDIM;

    // Issue all 8 target loads (2 rows x 4 float4) before consuming: max MLP.
    float4 a0[4], a1[4];
    #pragma unroll
    for (int j = 0; j < 4; ++j) {
        const int k = (j << 8) + (lane << 2);
        a0[j] = *(const float4*)(t0 + k);
        a1[j] = *(const float4*)(t1 + k);
    }

    float acc0 = 0.0f, acc1 = 0.0f;
    #pragma unroll
    for (int j = 0; j < 4; ++j) {
        acc0 += a0[j].x * w[j].x + a0[j].y * w[j].y + a0[j].z * w[j].z + a0[j].w * w[j].w;
        acc1 += a1[j].x * w[j].x + a1[j].y * w[j].y + a1[j].z * w[j].z + a1[j].w * w[j].w;
    }

    // 64-lane wave reduction (two values, interleaved for ILP)
    #pragma unroll
    for (int off = 32; off > 0; off >>= 1) {
        acc0 += __shfl_down(acc0, off, 64);
        acc1 += __shfl_down(acc1, off, 64);
    }

    if (lane == 0) {
        out[row0] = acc0;
        out[row1] = acc1;
    }
}

extern "C" void kernel_launch(void* const* d_in, const int* in_sizes, int n_in,
                              void* d_out, int out_size, void* d_ws, size_t ws_size,
                              hipStream_t stream) {
    const float* targets        = (const float*)d_in[0];
    const float* temporal_bases = (const float*)d_in[1];
    const float* scaling        = (const float*)d_in[2];
    const int*   batch_indices  = (const int*)d_in[3];
    float*       out            = (float*)d_out;

    const int B = in_sizes[0] / KDIM;          // 8192
    const int blocks = B / 8;                  // 4 waves/block x 2 rows/wave
    recompose_col1_kernel<<<blocks, 256, 0, stream>>>(
        targets, temporal_bases, scaling, batch_indices, out);
}